// Round 8
// baseline (1280.245 us; speedup 1.0000x reference)
//
#include <hip/hip_runtime.h>
#include <cmath>

#define BB 16
#define LL 512
#define FEAT 512
#define NLAB 4096
#define LLAB 32
#define EE 300
#define KK 4
#define TCONV (LLAB - KK + 1)  // 29

typedef __bf16 bf16x8 __attribute__((ext_vector_type(8)));
typedef __bf16 bf16x4 __attribute__((ext_vector_type(4)));
typedef float f32x4 __attribute__((ext_vector_type(4)));

// 16B global->LDS DMA (wave-uniform LDS base + lane*16; global addr is per-lane)
__device__ __forceinline__ void gl2lds16(const void* g, void* l) {
    __builtin_amdgcn_global_load_lds((const __attribute__((address_space(1))) unsigned int*)g,
                                     (__attribute__((address_space(3))) unsigned int*)l,
                                     16, 0, 0);
}

// ---------------------------------------------------------------------------
// Kernel 0: weight prep. conv_w [f][e][k] fp32 -> pre-split + PRE-SWIZZLED
// tiled bf16 layout consumed verbatim by global_load_lds:
//   chunk idx = ((fb*10 + ko)*128 + c)*4 + t   (16B chunks)
//   content   = elements e = ko*32 + q*8 + j,  q = t ^ ((c>>1)&3)   (XOR swizzle)
//   c = k*32 + fj  (f = fb*32 + fj, k = c>>5), e >= 300 zero-padded.
// ---------------------------------------------------------------------------
__global__ __launch_bounds__(256) void wprep(const float* __restrict__ conv_w,
                                             __bf16* __restrict__ wB_hi,
                                             __bf16* __restrict__ wB_lo) {
    const int idx = blockIdx.x * 256 + threadIdx.x;   // 0..81919
    const int fb  = idx / 5120;
    const int rem = idx - fb * 5120;
    const int ko  = rem >> 9;
    const int r2  = rem & 511;
    const int c   = r2 >> 2;
    const int t   = r2 & 3;
    const int q   = t ^ ((c >> 1) & 3);
    const int f   = fb * 32 + (c & 31);
    const int k   = c >> 5;
    bf16x8 h, l;
#pragma unroll
    for (int j = 0; j < 8; ++j) {
        const int e = ko * 32 + q * 8 + j;
        const float v = (e < 300) ? conv_w[((size_t)f * 300 + e) * 4 + k] : 0.f;
        h[j] = (__bf16)v;
        l[j] = (__bf16)(v - (float)h[j]);
    }
    *(bf16x8*)(wB_hi + (size_t)idx * 8) = h;
    *(bf16x8*)(wB_lo + (size_t)idx * 8) = l;
}

// ---------------------------------------------------------------------------
// Kernel 1: implicit-GEMM conv + shift-add(k) + bias + relu + maxpool -> lr0
// A loaded per-lane global->VGPR (16B-aligned, L2/L3-hot), hi/lo split in
// registers. LDS holds B only (2 x 16 KB double-buffer) -> LDS allows
// 4 blocks/CU (no launch_bounds min-wave attribute: plain 256, as in all
// previously-passing kernels; compiler lands ~110-120 VGPR naturally).
// ko=9 edge: valid tail e in [288,300). Three UNCONDITIONAL in-bounds
// aligned vector loads a=[288..291], b=[292..295], c=[296..299] from the
// row base; whole-vector select by quad (quad0: a,b; quad1: c,0; else 0,0).
// No conditional addressing anywhere -> provably no OOB.
// Frag layouts (verified m89/m91): A/B row/col=lane&15, k=quad*8+j;
//                                  D col=lane&15, row=quad*4+reg.
// ---------------------------------------------------------------------------
__global__ __launch_bounds__(256) void conv_mfma(const float* __restrict__ label_reps,
                                                 const __bf16* __restrict__ wB_hi,
                                                 const __bf16* __restrict__ wB_lo,
                                                 const float* __restrict__ conv_b,
                                                 float* __restrict__ lr0) {
    const int fb = blockIdx.x;   // 0..15
    const int nb = blockIdx.y;   // 0..1023
    const int tid = threadIdx.x;
    const int wave = tid >> 6;
    const int lane = tid & 63;
    const int quad = lane >> 4;
    const int l16  = lane & 15;

    // per buf: Bh [0,8192), Bl [8192,16384)
    __shared__ __align__(16) char lds[2][16384];

    const char* bh_g = (const char*)wB_hi + (size_t)fb * 10 * 8192;
    const char* bl_g = (const char*)wB_lo + (size_t)fb * 10 * 8192;

    // A row pointers (lane-invariant across ko); 16B-aligned:
    // (row*300 + e0 + quad*8)*4 with row*1200 % 16 == 0, e0%32==0.
    const float* pA0 = label_reps + (size_t)(nb * 128 + wave * 32 + l16) * 300 + quad * 8;
    const float* pA1 = pA0 + 16 * 300;

    f32x4 acc[2][8];   // [ri][cj]; cj: k = cj>>1, fhalf = cj&1
#pragma unroll
    for (int ri = 0; ri < 2; ++ri)
#pragma unroll
        for (int cj = 0; cj < 8; ++cj) acc[ri][cj] = (f32x4){0.f, 0.f, 0.f, 0.f};

    auto stageB = [&](int buf, int ko) {
        char* base = &lds[buf][0];
        const char* bh = bh_g + (size_t)ko * 8192;
        const char* bl = bl_g + (size_t)ko * 8192;
#pragma unroll
        for (int rnd = 0; rnd < 2; ++rnd) {
            const int o = rnd * 4096 + tid * 16;
            gl2lds16(bh + o, base + o);
            gl2lds16(bl + o, base + 8192 + o);
        }
    };

    stageB(0, 0);
    __syncthreads();

    const int bq = quad ^ ((l16 >> 1) & 3);    // == quad ^ ((brow>>1)&3)

    for (int ko = 0; ko < 10; ++ko) {
        const int buf = ko & 1;

        // ---- A raw loads first (issue early), then B prefetch DMA ----
        f32x4 v0[2], v1[2];
        if (ko < 9) {
#pragma unroll
            for (int ri = 0; ri < 2; ++ri) {
                const float* p = (ri ? pA1 : pA0) + ko * 32;
                v0[ri] = *(const f32x4*)(p);
                v1[ri] = *(const f32x4*)(p + 4);
            }
        } else {  // ko == 9: tail e in [288,300); unconditional in-bounds loads
#pragma unroll
            for (int ri = 0; ri < 2; ++ri) {
                const float* rb = (ri ? pA1 : pA0) - quad * 8 + 288;  // row elem 288
                const f32x4 a = *(const f32x4*)(rb);       // 288..291
                const f32x4 bb = *(const f32x4*)(rb + 4);  // 292..295
                const f32x4 cc = *(const f32x4*)(rb + 8);  // 296..299
                const f32x4 z = (f32x4){0.f, 0.f, 0.f, 0.f};
                v0[ri] = (quad == 0) ? a : ((quad == 1) ? cc : z);
                v1[ri] = (quad == 0) ? bb : z;
            }
        }
        if (ko < 9) stageB(buf ^ 1, ko + 1);   // prefetch stays in flight over MFMA

        // ---- split hi/lo in registers ----
        bf16x8 ah[2], al[2];
#pragma unroll
        for (int ri = 0; ri < 2; ++ri) {
            bf16x8 h, l;
#pragma unroll
            for (int j = 0; j < 4; ++j) {
                h[j]     = (__bf16)v0[ri][j]; l[j]     = (__bf16)(v0[ri][j] - (float)h[j]);
                h[4 + j] = (__bf16)v1[ri][j]; l[4 + j] = (__bf16)(v1[ri][j] - (float)h[4 + j]);
            }
            ah[ri] = h; al[ri] = l;
        }

        // ---- MFMA: 8 cj x 2 ri x 3 passes; B from LDS ----
        const char* base = &lds[buf][0];
#pragma unroll
        for (int cj = 0; cj < 8; ++cj) {
            const int brow = cj * 16 + l16;
            const bf16x8 bh = *(const bf16x8*)(base + brow * 64 + bq * 16);
            const bf16x8 bl = *(const bf16x8*)(base + 8192 + brow * 64 + bq * 16);
#pragma unroll
            for (int ri = 0; ri < 2; ++ri) {
                acc[ri][cj] = __builtin_amdgcn_mfma_f32_16x16x32_bf16(ah[ri], bh, acc[ri][cj], 0, 0, 0);
                acc[ri][cj] = __builtin_amdgcn_mfma_f32_16x16x32_bf16(ah[ri], bl, acc[ri][cj], 0, 0, 0);
                acc[ri][cj] = __builtin_amdgcn_mfma_f32_16x16x32_bf16(al[ri], bh, acc[ri][cj], 0, 0, 0);
            }
        }
        __syncthreads();
    }
    // ---- epilogue: h[t][f] = sum_k C[t+k][k], then max_t, +bias, relu ----
    const int label = nb * 4 + wave;
#pragma unroll
    for (int fh = 0; fh < 2; ++fh) {
        float m = -INFINITY;
#pragma unroll
        for (int t = 0; t < TCONV; ++t) {
            float loc = 0.f;
#pragma unroll
            for (int k = 0; k < KK; ++k) {
                const int r = t + k;                 // 0..31
                const float v = acc[r >> 4][k * 2 + fh][r & 3];
                loc += (((r >> 2) & 3) == quad) ? v : 0.f;
            }
            loc += __shfl_xor(loc, 16);
            loc += __shfl_xor(loc, 32);
            m = fmaxf(m, loc);
        }
        if (quad == 0) {
            const int f = fb * 32 + fh * 16 + l16;
            lr0[(size_t)label * FEAT + f] = fmaxf(m + conv_b[f], 0.f);
        }
    }
}

// ---------------------------------------------------------------------------
// Kernel 2: lr = lr0 @ lin_w^T + lin_b, epilogue split -> lr_hi/lr_lo (bf16)
// ---------------------------------------------------------------------------
__global__ __launch_bounds__(256) void linear_kernel(const float* __restrict__ lr0,
                                                     const float* __restrict__ lin_w,
                                                     const float* __restrict__ lin_b,
                                                     __bf16* __restrict__ lr_hi,
                                                     __bf16* __restrict__ lr_lo) {
    const int m0 = blockIdx.x * 64;
    const int i0 = blockIdx.y * 64;
    const int tid = threadIdx.x;
    const int tx = tid & 15;
    const int ty = tid >> 4;
    __shared__ float As[16][65];
    __shared__ float Bs[16][65];
    float acc[4][4] = {};

    for (int k0 = 0; k0 < 512; k0 += 16) {
        const int k = tid & 15, m = tid >> 4;
#pragma unroll
        for (int p = 0; p < 4; ++p)
            As[k][m + p*16] = lr0[(size_t)(m0 + m + p*16) * 512 + k0 + k];
#pragma unroll
        for (int p = 0; p < 4; ++p)
            Bs[k][m + p*16] = lin_w[(size_t)(i0 + m + p*16) * 512 + k0 + k];
        __syncthreads();
#pragma unroll
        for (int kk = 0; kk < 16; ++kk) {
            float a[4], b[4];
#pragma unroll
            for (int r = 0; r < 4; ++r) { a[r] = As[kk][ty*4 + r]; b[r] = Bs[kk][tx*4 + r]; }
#pragma unroll
            for (int ar = 0; ar < 4; ++ar)
#pragma unroll
                for (int br = 0; br < 4; ++br)
                    acc[ar][br] = fmaf(a[ar], b[br], acc[ar][br]);
        }
        __syncthreads();
    }
#pragma unroll
    for (int ar = 0; ar < 4; ++ar) {
        const int row = m0 + ty*4 + ar;
        const int col = i0 + tx*4;
#pragma unroll
        for (int br = 0; br < 4; ++br) {
            float v = acc[ar][br] + lin_b[col + br];
            __bf16 h = (__bf16)v;
            lr_hi[(size_t)row * 512 + col + br] = h;
            lr_lo[(size_t)row * 512 + col + br] = (__bf16)(v - (float)h);
        }
    }
}

// ---------------------------------------------------------------------------
// Kernel 2b: split x -> x_hi/x_lo (bf16 [b][l][f]) + xT (bf16 [b][f][l])
// ---------------------------------------------------------------------------
__global__ __launch_bounds__(256) void split_x(const float* __restrict__ x,
                                               __bf16* __restrict__ x_hi,
                                               __bf16* __restrict__ x_lo,
                                               __bf16* __restrict__ xT) {
    const int b  = blockIdx.z;
    const int l0 = blockIdx.y * 64;
    const int f0 = blockIdx.x * 64;
    const int tid = threadIdx.x;
    __shared__ __bf16 tile[64][65];
    const int j = tid & 63;
#pragma unroll
    for (int s = 0; s < 16; ++s) {
        const int rr = (tid >> 6) + s * 4;
        const size_t o = ((size_t)(b * 512 + l0 + rr)) * 512 + f0 + j;
        float v = x[o];
        __bf16 h = (__bf16)v;
        x_hi[o] = h;
        x_lo[o] = (__bf16)(v - (float)h);
        tile[rr][j] = h;
    }
    __syncthreads();
#pragma unroll
    for (int s = 0; s < 16; ++s) {
        const int ff = (tid >> 6) + s * 4;
        xT[((size_t)(b * 512 + f0 + ff)) * 512 + l0 + j] = tile[j][ff];
    }
}

// ---------------------------------------------------------------------------
// Kernel 3: de-flashed attention, 32 labels/block (2 n-tiles). Unchanged
// from round 3 (verified).
// ---------------------------------------------------------------------------
__global__ __launch_bounds__(256) void attention_mfma(const __bf16* __restrict__ x_hi,
                                                      const __bf16* __restrict__ x_lo,
                                                      const __bf16* __restrict__ xT,
                                                      const __bf16* __restrict__ lr_hi,
                                                      const __bf16* __restrict__ lr_lo,
                                                      float* __restrict__ out) {
    const int b  = blockIdx.y;
    const int n0 = blockIdx.x * 32;
    const int tid  = threadIdx.x;
    const int wave = tid >> 6;
    const int lane = tid & 63;
    const int quad = lane >> 4;
    const int l16  = lane & 15;

    __shared__ float wavemax[4][32];
    __shared__ float wavesum[4][32];
    // row stride 520 bf16 = 1040 B = 65 x 16B slots -> uniform bank spread
    __shared__ __align__(16) __bf16 Ps[32][520];

    // ---- phase A: full S for 2 n-tiles, no barriers. k outer, lt inner.
    f32x4 sacc[2][8];
#pragma unroll
    for (int nt = 0; nt < 2; ++nt)
#pragma unroll
        for (int lt = 0; lt < 8; ++lt) sacc[nt][lt] = (f32x4){0.f, 0.f, 0.f, 0.f};

    const __bf16* lrh0 = lr_hi + (size_t)(n0 + l16) * FEAT + quad * 8;
    const __bf16* lrl0 = lr_lo + (size_t)(n0 + l16) * FEAT + quad * 8;
    const __bf16* lrh1 = lrh0 + (size_t)16 * FEAT;
    const __bf16* lrl1 = lrl0 + (size_t)16 * FEAT;
    const __bf16* xh0 = x_hi + ((size_t)(b * LL + wave * 128 + l16)) * FEAT + quad * 8;
    const __bf16* xl0 = x_lo + ((size_t)(b * LL + wave * 128 + l16)) * FEAT + quad * 8;

#pragma unroll 2
    for (int ks = 0; ks < 16; ++ks) {
        const int k0 = ks * 32;
        const bf16x8 ah0 = *(const bf16x8*)(lrh0 + k0);
        const bf16x8 al0 = *(const bf16x8*)(lrl0 + k0);
        const bf16x8 ah1 = *(const bf16x8*)(lrh1 + k0);
        const bf16x8 al1 = *(const bf16x8*)(lrl1 + k0);
#pragma unroll
        for (int lt = 0; lt < 8; ++lt) {
            const bf16x8 bh = *(const bf16x8*)(xh0 + lt * 16 * FEAT + k0);
            const bf16x8 bl = *(const bf16x8*)(xl0 + lt * 16 * FEAT + k0);
            sacc[0][lt] = __builtin_amdgcn_mfma_f32_16x16x32_bf16(ah0, bh, sacc[0][lt], 0, 0, 0);
            sacc[0][lt] = __builtin_amdgcn_mfma_f32_16x16x32_bf16(ah0, bl, sacc[0][lt], 0, 0, 0);
            sacc[0][lt] = __builtin_amdgcn_mfma_f32_16x16x32_bf16(al0, bh, sacc[0][lt], 0, 0, 0);
            sacc[1][lt] = __builtin_amdgcn_mfma_f32_16x16x32_bf16(ah1, bh, sacc[1][lt], 0, 0, 0);
            sacc[1][lt] = __builtin_amdgcn_mfma_f32_16x16x32_bf16(ah1, bl, sacc[1][lt], 0, 0, 0);
            sacc[1][lt] = __builtin_amdgcn_mfma_f32_16x16x32_bf16(al1, bh, sacc[1][lt], 0, 0, 0);
        }
    }

    // ---- phase B: one softmax pass. lane holds S[n = nt*16+quad*4+r][l = wave*128+lt*16+l16]
    float m[2][4];
#pragma unroll
    for (int nt = 0; nt < 2; ++nt)
#pragma unroll
        for (int r = 0; r < 4; ++r) {
            float v = sacc[nt][0][r];
#pragma unroll
            for (int lt = 1; lt < 8; ++lt) v = fmaxf(v, sacc[nt][lt][r]);
            v = fmaxf(v, __shfl_xor(v, 1));
            v = fmaxf(v, __shfl_xor(v, 2));
            v = fmaxf(v, __shfl_xor(v, 4));
            v = fmaxf(v, __shfl_xor(v, 8));
            m[nt][r] = v;
        }
    if (l16 == 0) {
#pragma unroll
        for (int nt = 0; nt < 2; ++nt)
#pragma unroll
            for (int r = 0; r < 4; ++r) wavemax[wave][nt * 16 + quad * 4 + r] = m[nt][r];
    }
    __syncthreads();
    float dsum[2][4];
#pragma unroll
    for (int nt = 0; nt < 2; ++nt)
#pragma unroll
        for (int r = 0; r < 4; ++r) {
            const int n = nt * 16 + quad * 4 + r;
            m[nt][r] = fmaxf(fmaxf(wavemax[0][n], wavemax[1][n]),
                             fmaxf(wavemax[2][n], wavemax[3][n]));
            float s = 0.f;
#pragma unroll
            for (int lt = 0; lt < 8; ++lt) {
                const float p = __expf(sacc[nt][lt][r] - m[nt][r]);
                s += p;
                Ps[n][wave * 128 + lt * 16 + l16] = (__bf16)p;
            }
            s += __shfl_xor(s, 1);
            s += __shfl_xor(s, 2);
            s += __shfl_xor(s, 4);
            s += __shfl_xor(s, 8);
            dsum[nt][r] = s;
        }
    if (l16 == 0) {
#pragma unroll
        for (int nt = 0; nt < 2; ++nt)
#pragma unroll
            for (int r = 0; r < 4; ++r) wavesum[wave][nt * 16 + quad * 4 + r] = dsum[nt][r];
    }
    __syncthreads();
    float dinv[2][4];
#pragma unroll
    for (int nt = 0; nt < 2; ++nt)
#pragma unroll
        for (int r = 0; r < 4; ++r) {
            const int n = nt * 16 + quad * 4 + r;
            dinv[nt][r] = 1.0f / (wavesum[0][n] + wavesum[1][n] + wavesum[2][n] + wavesum[3][n]);
        }

    // ---- phase C: PV. wave owns f-range wave*128; A=Ps rows(n), B=xT rows(f).
    // Each xT fragment feeds 2 n-tiles.
    f32x4 oacc[2][8];
#pragma unroll
    for (int nt = 0; nt < 2; ++nt)
#pragma unroll
        for (int fs = 0; fs < 8; ++fs) oacc[nt][fs] = (f32x4){0.f, 0.f, 0.f, 0.f};

    const __bf16* xtb = xT + ((size_t)(b * FEAT + wave * 128 + l16)) * LL + quad * 8;
#pragma unroll 2
    for (int kb = 0; kb < 16; ++kb) {
        const bf16x8 ap0 = *(const bf16x8*)&Ps[l16][kb * 32 + quad * 8];
        const bf16x8 ap1 = *(const bf16x8*)&Ps[16 + l16][kb * 32 + quad * 8];
#pragma unroll
        for (int fs = 0; fs < 8; ++fs) {
            const bf16x8 bfrag = *(const bf16x8*)(xtb + (size_t)fs * 16 * LL + kb * 32);
            oacc[0][fs] = __builtin_amdgcn_mfma_f32_16x16x32_bf16(ap0, bfrag, oacc[0][fs], 0, 0, 0);
            oacc[1][fs] = __builtin_amdgcn_mfma_f32_16x16x32_bf16(ap1, bfrag, oacc[1][fs], 0, 0, 0);
        }
    }

#pragma unroll
    for (int nt = 0; nt < 2; ++nt)
#pragma unroll
        for (int fs = 0; fs < 8; ++fs) {
#pragma unroll
            for (int r = 0; r < 4; ++r) {
                const int n = n0 + nt * 16 + quad * 4 + r;
                const int f = wave * 128 + fs * 16 + l16;
                out[((size_t)(b * NLAB + n)) * FEAT + f] = oacc[nt][fs][r] * dinv[nt][r];
            }
        }
}

// ---------------------------------------------------------------------------
// Workspace layout (float-slot offsets), peak ~32 MB:
//   [0        .. 1048576)  lr_hi   (4096*512 bf16)
//   [1048576  .. 2097152)  lr_lo
//   [2097152  .. 2424832)  wB_hi   (16*10*128*4 chunks bf16, dead after conv)
//   [2424832  .. 2752512)  wB_lo   (dead after conv_mfma)
//   [2752528  .. 4849680)  lr0     (fp32, dead after linear_kernel)
//   [2097152  .. 4194304)  x_hi    (written by split_x, after linear)
//   [4194304  .. 6291456)  x_lo
//   [6291456  .. 8388608)  xT
// ---------------------------------------------------------------------------
extern "C" void kernel_launch(void* const* d_in, const int* in_sizes, int n_in,
                              void* d_out, int out_size, void* d_ws, size_t ws_size,
                              hipStream_t stream) {
    const float* x          = (const float*)d_in[0];  // (16,512,512)
    const float* label_reps = (const float*)d_in[1];  // (4096,32,300)
    const float* conv_w     = (const float*)d_in[2];  // (512,300,4)
    const float* conv_b     = (const float*)d_in[3];  // (512,)
    const float* lin_w      = (const float*)d_in[4];  // (512,512)
    const float* lin_b      = (const float*)d_in[5];  // (512,)
    float* out = (float*)d_out;

    float* wsf = (float*)d_ws;
    __bf16* lr_hi = (__bf16*)(wsf);
    __bf16* lr_lo = (__bf16*)(wsf + 1048576);
    __bf16* wB_hi = (__bf16*)(wsf + 2097152);
    __bf16* wB_lo = (__bf16*)(wsf + 2424832);
    float*  lr0   = wsf + 2752528;
    __bf16* x_hi  = (__bf16*)(wsf + 2097152);   // aliases wB/lr0 (dead by then)
    __bf16* x_lo  = (__bf16*)(wsf + 4194304);
    __bf16* xT    = (__bf16*)(wsf + 6291456);

    wprep<<<dim3(320), dim3(256), 0, stream>>>(conv_w, wB_hi, wB_lo);
    conv_mfma<<<dim3(16, 1024), dim3(256), 0, stream>>>(label_reps, wB_hi, wB_lo, conv_b, lr0);
    linear_kernel<<<dim3(64, 8), dim3(256), 0, stream>>>(lr0, lin_w, lin_b, lr_hi, lr_lo);
    split_x<<<dim3(8, 8, 16), dim3(256), 0, stream>>>(x, x_hi, x_lo, xT);
    attention_mfma<<<dim3(NLAB / 32, BB), dim3(256), 0, stream>>>(x_hi, x_lo, xT, lr_hi, lr_lo, out);
}